// Round 13
// baseline (267.553 us; speedup 1.0000x reference)
//
#include <hip/hip_runtime.h>

// One-way Chamfer (L1, K=1): out[0] = mean_i min_j ||x_i - y_j||_1 ; out[1..N] = 0
// N = M = 16384, D = 3, fp32.
//
// R13: algorithmic round. Brute force is parameter-exhausted at ~40us total
// (2.68e8 pairs, VALU floor ~27us + plumbing). Exact early-exit instead:
// L1 >= |dx|, so bucket pc2 into 512 x-slabs; each query scans its slab and
// expands left/right only while the slab x-bound < current min (bound given
// 1e-4 abs+rel slack -> scans a superset, stays exact). ~16x less pair work
// on Gaussian data. 8 lanes per query (uniform group decisions, shfl_xor
// min-combine). 3 dispatches, no memsets: build (1 block: minmax+hist+scan+
// scatter), query (512 blocks), finalize (zeros + sum).
// Determinism: scatter order inside a bucket is atomic-order nondeterministic
// but min over a fixed set is order-independent -> qmin bit-exact; expansion
// decisions depend only on set-mins -> same buckets scanned every call.

#define NB   512      // x-slabs
#define BTPB 1024     // build block size
#define QTPB 256
#define LPQ  8        // lanes cooperating per query
#define FTPB 256

__global__ __launch_bounds__(BTPB) void build_kernel(
    const float* __restrict__ pc2, float4* __restrict__ pts,
    int* __restrict__ base, float* __restrict__ hdr, int M) {
    __shared__ int hist[NB];
    __shared__ int scan[NB];
    __shared__ int cursor[NB];
    __shared__ float red[(BTPB / 64) * 2];
    __shared__ float s_lo, s_invw, s_w;
    const int t = threadIdx.x;

    // pass 0: min/max of pc2.x
    float lmin = 3.0e38f, lmax = -3.0e38f;
    for (int j = t; j < M; j += BTPB) {
        const float x = pc2[3 * j];
        lmin = fminf(lmin, x); lmax = fmaxf(lmax, x);
    }
#pragma unroll
    for (int off = 32; off; off >>= 1) {
        lmin = fminf(lmin, __shfl_down(lmin, off, 64));
        lmax = fmaxf(lmax, __shfl_down(lmax, off, 64));
    }
    if ((t & 63) == 0) { red[(t >> 6) * 2] = lmin; red[(t >> 6) * 2 + 1] = lmax; }
    __syncthreads();
    if (t == 0) {
        float mn = red[0], mx = red[1];
        for (int w2 = 1; w2 < BTPB / 64; ++w2) {
            mn = fminf(mn, red[w2 * 2]); mx = fmaxf(mx, red[w2 * 2 + 1]);
        }
        s_lo = mn;
        s_w  = (mx - mn) / (float)NB;
        s_invw = (mx > mn) ? ((float)NB / (mx - mn)) : 0.0f;
        hdr[0] = mn; hdr[1] = s_invw; hdr[2] = s_w;
    }
    if (t < NB) hist[t] = 0;
    __syncthreads();
    const float lo = s_lo, invw = s_invw;

    // pass 1: histogram
    for (int j = t; j < M; j += BTPB) {
        int b = (int)((pc2[3 * j] - lo) * invw);
        b = (b < 0) ? 0 : ((b > NB - 1) ? NB - 1 : b);
        atomicAdd(&hist[b], 1);
    }
    __syncthreads();

    // Hillis-Steele inclusive scan in LDS
    if (t < NB) scan[t] = hist[t];
    __syncthreads();
    for (int off = 1; off < NB; off <<= 1) {
        int v = 0;
        if (t < NB && t >= off) v = scan[t - off];
        __syncthreads();
        if (t < NB) scan[t] += v;
        __syncthreads();
    }
    if (t < NB) { const int b0 = scan[t] - hist[t]; base[t] = b0; cursor[t] = b0; }
    if (t == 0) base[NB] = M;
    __syncthreads();

    // pass 2: scatter into packed float4 (w unused)
    for (int j = t; j < M; j += BTPB) {
        const float x = pc2[3 * j], y = pc2[3 * j + 1], z = pc2[3 * j + 2];
        int b = (int)((x - lo) * invw);
        b = (b < 0) ? 0 : ((b > NB - 1) ? NB - 1 : b);
        const int pos = atomicAdd(&cursor[b], 1);
        pts[pos] = make_float4(x, y, z, 0.0f);
    }
}

#define SCAN_BUCKET(B)                                                     \
  {                                                                        \
    const int s_ = base[B], e_ = base[(B) + 1];                            \
    for (int j = s_ + g; j < e_; j += LPQ) {                               \
      const float4 p = pts[j];                                             \
      m = fminf(m, fabsf(qx - p.x) + fabsf(qy - p.y) + fabsf(qz - p.z));   \
    }                                                                      \
    m = fminf(m, __shfl_xor(m, 1, 64));                                    \
    m = fminf(m, __shfl_xor(m, 2, 64));                                    \
    m = fminf(m, __shfl_xor(m, 4, 64));                                    \
  }

__global__ __launch_bounds__(QTPB) void query_kernel(
    const float* __restrict__ pc1, const float* __restrict__ flow,
    const float4* __restrict__ pts, const int* __restrict__ base,
    const float* __restrict__ hdr, float* __restrict__ qmin, int N) {
    const int tid = blockIdx.x * QTPB + threadIdx.x;
    const int q = tid >> 3;        // LPQ = 8
    const int g = tid & 7;
    if (q >= N) return;

    const float lo = hdr[0], invw = hdr[1], w = hdr[2];
    const float qx = pc1[3 * q]     + flow[3 * q];
    const float qy = pc1[3 * q + 1] + flow[3 * q + 1];
    const float qz = pc1[3 * q + 2] + flow[3 * q + 2];

    int b0 = (int)((qx - lo) * invw);
    b0 = (b0 < 0) ? 0 : ((b0 > NB - 1) ? NB - 1 : b0);

    float m = 3.0e38f;
    SCAN_BUCKET(b0);

    if (invw != 0.0f) {            // degenerate range: bucket 0 held everything
        const float qlo = qx - lo;
        int bl = b0 - 1, br = b0 + 1;
        bool goL = (bl >= 0), goR = (br <= NB - 1);
        while (goL || goR) {
            if (goL) {
                // lower bound on |qx - y.x| for all y in buckets <= bl
                const float bnd = qlo - (float)(bl + 1) * w;
                if (bnd * 0.9999f - 1.0e-4f >= m) goL = false;
                else { SCAN_BUCKET(bl); --bl; goL = (bl >= 0); }
            }
            if (goR) {
                const float bnd = (float)br * w - qlo;
                if (bnd * 0.9999f - 1.0e-4f >= m) goR = false;
                else { SCAN_BUCKET(br); ++br; goR = (br <= NB - 1); }
            }
        }
    }
    if (g == 0) qmin[q] = m;
}

// zeros for out[1..]; block 0 sums qmin -> out[0]
__global__ __launch_bounds__(FTPB) void finalize_kernel(
    const float* __restrict__ qmin, float* __restrict__ out,
    int N, int out_size, float invN) {
    const int t = threadIdx.x;
    const int stride = gridDim.x * FTPB;
    for (int k = blockIdx.x * FTPB + t; 1 + k < out_size; k += stride)
        out[1 + k] = 0.0f;

    if (blockIdx.x == 0) {
        float s = 0.0f;
        const float4* p4 = (const float4*)qmin;
        const int n4 = N >> 2;
        for (int k = t; k < n4; k += FTPB) {
            const float4 v = p4[k];
            s += v.x + v.y + v.z + v.w;
        }
        for (int k = (n4 << 2) + t; k < N; k += FTPB) s += qmin[k];
#pragma unroll
        for (int off = 32; off; off >>= 1) s += __shfl_down(s, off, 64);
        __shared__ float ls[FTPB / 64];
        if ((t & 63) == 0) ls[t >> 6] = s;
        __syncthreads();
        if (t == 0) {
            float tot = 0.0f;
            for (int w2 = 0; w2 < FTPB / 64; ++w2) tot += ls[w2];
            out[0] = tot * invN;
        }
    }
}

extern "C" void kernel_launch(void* const* d_in, const int* in_sizes, int n_in,
                              void* d_out, int out_size, void* d_ws, size_t ws_size,
                              hipStream_t stream) {
    const float* pc1  = (const float*)d_in[0];
    const float* flow = (const float*)d_in[1];
    const float* pc2  = (const float*)d_in[2];
    float* out = (float*)d_out;

    const int N = in_sizes[0] / 3;
    const int M = in_sizes[2] / 3;

    char* ws = (char*)d_ws;
    float*  hdr  = (float*)ws;                         // 3 floats
    int*    base = (int*)(ws + 64);                    // NB+1 ints (2052 B)
    float4* pts  = (float4*)(ws + 4096);               // M float4
    float*  qmin = (float*)(ws + 4096 + (size_t)M * 16);

    build_kernel<<<1, BTPB, 0, stream>>>(pc2, pts, base, hdr, M);

    const int qblocks = (N * LPQ + QTPB - 1) / QTPB;   // 512
    query_kernel<<<qblocks, QTPB, 0, stream>>>(pc1, flow, pts, base, hdr, qmin, N);

    finalize_kernel<<<64, FTPB, 0, stream>>>(qmin, out, N, out_size, 1.0f / (float)N);
}

// Round 14
// 73.628 us; speedup vs baseline: 3.6338x; 3.6338x over previous
//
#include <hip/hip_runtime.h>

// One-way Chamfer (L1, K=1): out[0] = mean_i min_j ||x_i - y_j||_1 ; out[1..N] = 0
// N = M = 16384, D = 3, fp32.
//
// R14: keep R13's exact x-slab bucketing (absmax was 0.0) but fix the query
// SHAPE: R13 was latency-bound (260us, 5.5% occupancy) from serial divergent
// bucket walks. Now: ONE WAVE PER QUERY, two fixed phases, no serial walk.
//   A: scan buckets b0+-1 (~96 pts, coalesced float4) -> upper bound m0.
//   B: window = all buckets intersecting [qx-m0, qx+m0] (+1 slack bucket on
//      each side, absorbs FP bucket rounding); scan once, contiguous.
// Points outside window have |dx| > m0 >= d_true -> exact. All decisions
// wave-uniform (zero divergence); 16384 waves give 32 waves/CU of TLP.
// Determinism: mins over fixed sets; scatter order inside buckets never
// affects a min or a window -> bit-identical across replays.

#define NB   512      // x-slabs
#define BTPB 1024     // build block size
#define QTPB 256      // 4 waves -> 4 queries per block
#define FTPB 256

__global__ __launch_bounds__(BTPB) void build_kernel(
    const float* __restrict__ pc2, float4* __restrict__ pts,
    int* __restrict__ base, float* __restrict__ hdr, int M) {
    __shared__ int hist[NB];
    __shared__ int scan[NB];
    __shared__ int cursor[NB];
    __shared__ float red[(BTPB / 64) * 2];
    __shared__ float s_lo, s_invw;
    const int t = threadIdx.x;

    // pass 0: min/max of pc2.x
    float lmin = 3.0e38f, lmax = -3.0e38f;
    for (int j = t; j < M; j += BTPB) {
        const float x = pc2[3 * j];
        lmin = fminf(lmin, x); lmax = fmaxf(lmax, x);
    }
#pragma unroll
    for (int off = 32; off; off >>= 1) {
        lmin = fminf(lmin, __shfl_down(lmin, off, 64));
        lmax = fmaxf(lmax, __shfl_down(lmax, off, 64));
    }
    if ((t & 63) == 0) { red[(t >> 6) * 2] = lmin; red[(t >> 6) * 2 + 1] = lmax; }
    __syncthreads();
    if (t == 0) {
        float mn = red[0], mx = red[1];
        for (int w2 = 1; w2 < BTPB / 64; ++w2) {
            mn = fminf(mn, red[w2 * 2]); mx = fmaxf(mx, red[w2 * 2 + 1]);
        }
        s_lo = mn;
        s_invw = (mx > mn) ? ((float)NB / (mx - mn)) : 0.0f;
        hdr[0] = mn; hdr[1] = s_invw;
    }
    if (t < NB) hist[t] = 0;
    __syncthreads();
    const float lo = s_lo, invw = s_invw;

    // pass 1: histogram
    for (int j = t; j < M; j += BTPB) {
        int b = (int)((pc2[3 * j] - lo) * invw);
        b = (b < 0) ? 0 : ((b > NB - 1) ? NB - 1 : b);
        atomicAdd(&hist[b], 1);
    }
    __syncthreads();

    // Hillis-Steele inclusive scan in LDS
    if (t < NB) scan[t] = hist[t];
    __syncthreads();
    for (int off = 1; off < NB; off <<= 1) {
        int v = 0;
        if (t < NB && t >= off) v = scan[t - off];
        __syncthreads();
        if (t < NB) scan[t] += v;
        __syncthreads();
    }
    if (t < NB) { const int b0 = scan[t] - hist[t]; base[t] = b0; cursor[t] = b0; }
    if (t == 0) base[NB] = M;
    __syncthreads();

    // pass 2: scatter into packed float4 (w unused)
    for (int j = t; j < M; j += BTPB) {
        const float x = pc2[3 * j], y = pc2[3 * j + 1], z = pc2[3 * j + 2];
        int b = (int)((x - lo) * invw);
        b = (b < 0) ? 0 : ((b > NB - 1) ? NB - 1 : b);
        const int pos = atomicAdd(&cursor[b], 1);
        pts[pos] = make_float4(x, y, z, 0.0f);
    }
}

__global__ __launch_bounds__(QTPB) void query_kernel(
    const float* __restrict__ pc1, const float* __restrict__ flow,
    const float4* __restrict__ pts, const int* __restrict__ base,
    const float* __restrict__ hdr, float* __restrict__ qmin, int N) {
    const int lane = threadIdx.x & 63;
    const int q = blockIdx.x * (QTPB / 64) + (threadIdx.x >> 6);
    if (q >= N) return;

    const float lo = hdr[0], invw = hdr[1];
    const float qx = pc1[3 * q]     + flow[3 * q];
    const float qy = pc1[3 * q + 1] + flow[3 * q + 1];
    const float qz = pc1[3 * q + 2] + flow[3 * q + 2];

    int b0 = (int)fminf(fmaxf((qx - lo) * invw, 0.0f), (float)(NB - 1));

    // phase A: buckets b0-1 .. b0+1 (coalesced, wave-uniform range)
    float m = 3.0e38f;
    {
        const int s = base[(b0 > 0) ? b0 - 1 : 0];
        const int e = base[(b0 + 2 < NB) ? b0 + 2 : NB];
        for (int j = s + lane; j < e; j += 64) {
            const float4 p = pts[j];
            m = fminf(m, fabsf(qx - p.x) + fabsf(qy - p.y) + fabsf(qz - p.z));
        }
    }
#pragma unroll
    for (int k = 1; k < 64; k <<= 1) m = fminf(m, __shfl_xor(m, k, 64));

    // phase B: final window from the upper bound m (one shot, no walk)
    {
        const int bl0 = (int)fminf(fmaxf((qx - m - lo) * invw, 0.0f), (float)(NB - 1));
        const int br0 = (int)fminf(fmaxf((qx + m - lo) * invw, 0.0f), (float)(NB - 1));
        const int bl = (bl0 > 0) ? bl0 - 1 : 0;            // +-1 slack bucket
        const int br = (br0 + 1 < NB - 1) ? br0 + 1 : NB - 1;
        const int s = base[bl], e = base[br + 1];
        for (int j = s + lane; j < e; j += 64) {
            const float4 p = pts[j];
            m = fminf(m, fabsf(qx - p.x) + fabsf(qy - p.y) + fabsf(qz - p.z));
        }
    }
#pragma unroll
    for (int k = 1; k < 64; k <<= 1) m = fminf(m, __shfl_xor(m, k, 64));

    if (lane == 0) qmin[q] = m;
}

// zeros for out[1..]; block 0 sums qmin -> out[0]
__global__ __launch_bounds__(FTPB) void finalize_kernel(
    const float* __restrict__ qmin, float* __restrict__ out,
    int N, int out_size, float invN) {
    const int t = threadIdx.x;
    const int stride = gridDim.x * FTPB;
    for (int k = blockIdx.x * FTPB + t; 1 + k < out_size; k += stride)
        out[1 + k] = 0.0f;

    if (blockIdx.x == 0) {
        float s = 0.0f;
        const float4* p4 = (const float4*)qmin;
        const int n4 = N >> 2;
        for (int k = t; k < n4; k += FTPB) {
            const float4 v = p4[k];
            s += v.x + v.y + v.z + v.w;
        }
        for (int k = (n4 << 2) + t; k < N; k += FTPB) s += qmin[k];
#pragma unroll
        for (int off = 32; off; off >>= 1) s += __shfl_down(s, off, 64);
        __shared__ float ls[FTPB / 64];
        if ((t & 63) == 0) ls[t >> 6] = s;
        __syncthreads();
        if (t == 0) {
            float tot = 0.0f;
            for (int w2 = 0; w2 < FTPB / 64; ++w2) tot += ls[w2];
            out[0] = tot * invN;
        }
    }
}

extern "C" void kernel_launch(void* const* d_in, const int* in_sizes, int n_in,
                              void* d_out, int out_size, void* d_ws, size_t ws_size,
                              hipStream_t stream) {
    const float* pc1  = (const float*)d_in[0];
    const float* flow = (const float*)d_in[1];
    const float* pc2  = (const float*)d_in[2];
    float* out = (float*)d_out;

    const int N = in_sizes[0] / 3;
    const int M = in_sizes[2] / 3;

    char* ws = (char*)d_ws;
    float*  hdr  = (float*)ws;                         // 2 floats
    int*    base = (int*)(ws + 64);                    // NB+1 ints
    float4* pts  = (float4*)(ws + 4096);               // M float4
    float*  qmin = (float*)(ws + 4096 + (size_t)M * 16);

    build_kernel<<<1, BTPB, 0, stream>>>(pc2, pts, base, hdr, M);

    const int qblocks = (N + (QTPB / 64) - 1) / (QTPB / 64);   // 4096
    query_kernel<<<qblocks, QTPB, 0, stream>>>(pc1, flow, pts, base, hdr, qmin, N);

    finalize_kernel<<<64, FTPB, 0, stream>>>(qmin, out, N, out_size, 1.0f / (float)N);
}

// Round 15
// 54.447 us; speedup vs baseline: 4.9140x; 1.3523x over previous
//
#include <hip/hip_runtime.h>

// One-way Chamfer (L1, K=1): out[0] = mean_i min_j ||x_i - y_j||_1 ; out[1..N] = 0
// N = M = 16384, D = 3, fp32.
//
// R15: R14's query was latency-bound (54us vs ~2us of issue; 1 load in
// flight, VGPR=24). Fixes: (1) 4-way unrolled window scan, 4 independent
// accumulators + batched float4 loads; (2) phase B skips the phase-A range
// (scan [s,sA) and [eA,e) only); (3) query waves write out[1+q]=0 (zeros
// for free), finalize = pure single-block sum; (4) unroll-4 in build passes.
// Algorithm unchanged (exact x-slab window, wave-per-query, wave-uniform):
//   A: scan slabs b0+-1 -> upper bound m; B: scan all slabs intersecting
//   [qx-m, qx+m] (+-1 slack). NN's slab is provably inside (monotone FP
//   bucket map). Mins over fixed sets -> bit-deterministic across replays.

#define NB   512      // x-slabs
#define BTPB 1024     // build block size
#define QTPB 256      // 4 waves -> 4 queries per block
#define FTPB 1024

__global__ __launch_bounds__(BTPB) void build_kernel(
    const float* __restrict__ pc2, float4* __restrict__ pts,
    int* __restrict__ base, float* __restrict__ hdr, int M) {
    __shared__ int hist[NB];
    __shared__ int scan[NB];
    __shared__ int cursor[NB];
    __shared__ float red[(BTPB / 64) * 2];
    __shared__ float s_lo, s_invw;
    const int t = threadIdx.x;

    // pass 0: min/max of pc2.x (2 accumulator pairs for ILP)
    float mn0 = 3.0e38f, mx0 = -3.0e38f, mn1 = 3.0e38f, mx1 = -3.0e38f;
    for (int j = t; j < M; j += 2 * BTPB) {
        const float x0 = pc2[3 * j];
        mn0 = fminf(mn0, x0); mx0 = fmaxf(mx0, x0);
        if (j + BTPB < M) {
            const float x1 = pc2[3 * (j + BTPB)];
            mn1 = fminf(mn1, x1); mx1 = fmaxf(mx1, x1);
        }
    }
    float lmin = fminf(mn0, mn1), lmax = fmaxf(mx0, mx1);
#pragma unroll
    for (int off = 32; off; off >>= 1) {
        lmin = fminf(lmin, __shfl_down(lmin, off, 64));
        lmax = fmaxf(lmax, __shfl_down(lmax, off, 64));
    }
    if ((t & 63) == 0) { red[(t >> 6) * 2] = lmin; red[(t >> 6) * 2 + 1] = lmax; }
    __syncthreads();
    if (t == 0) {
        float mn = red[0], mx = red[1];
        for (int w2 = 1; w2 < BTPB / 64; ++w2) {
            mn = fminf(mn, red[w2 * 2]); mx = fmaxf(mx, red[w2 * 2 + 1]);
        }
        s_lo = mn;
        s_invw = (mx > mn) ? ((float)NB / (mx - mn)) : 0.0f;
        hdr[0] = mn; hdr[1] = s_invw;
    }
    if (t < NB) hist[t] = 0;
    __syncthreads();
    const float lo = s_lo, invw = s_invw;

    // pass 1: histogram
#pragma unroll 4
    for (int j = t; j < M; j += BTPB) {
        int b = (int)((pc2[3 * j] - lo) * invw);
        b = (b < 0) ? 0 : ((b > NB - 1) ? NB - 1 : b);
        atomicAdd(&hist[b], 1);
    }
    __syncthreads();

    // Hillis-Steele inclusive scan in LDS
    if (t < NB) scan[t] = hist[t];
    __syncthreads();
    for (int off = 1; off < NB; off <<= 1) {
        int v = 0;
        if (t < NB && t >= off) v = scan[t - off];
        __syncthreads();
        if (t < NB) scan[t] += v;
        __syncthreads();
    }
    if (t < NB) { const int b0 = scan[t] - hist[t]; base[t] = b0; cursor[t] = b0; }
    if (t == 0) base[NB] = M;
    __syncthreads();

    // pass 2: scatter into packed float4 (w unused)
#pragma unroll 2
    for (int j = t; j < M; j += BTPB) {
        const float x = pc2[3 * j], y = pc2[3 * j + 1], z = pc2[3 * j + 2];
        int b = (int)((x - lo) * invw);
        b = (b < 0) ? 0 : ((b > NB - 1) ? NB - 1 : b);
        const int pos = atomicAdd(&cursor[b], 1);
        pts[pos] = make_float4(x, y, z, 0.0f);
    }
}

__global__ __launch_bounds__(QTPB) void query_kernel(
    const float* __restrict__ pc1, const float* __restrict__ flow,
    const float4* __restrict__ pts, const int* __restrict__ base,
    const float* __restrict__ hdr, float* __restrict__ qmin,
    float* __restrict__ out, int N) {
    const int lane = threadIdx.x & 63;
    const int q = blockIdx.x * (QTPB / 64) + (threadIdx.x >> 6);
    if (q >= N) return;

    const float lo = hdr[0], invw = hdr[1];
    const float qx = pc1[3 * q]     + flow[3 * q];
    const float qy = pc1[3 * q + 1] + flow[3 * q + 1];
    const float qz = pc1[3 * q + 2] + flow[3 * q + 2];

    const int b0 = (int)fminf(fmaxf((qx - lo) * invw, 0.0f), (float)(NB - 1));

    float m0 = 3.0e38f, m1 = 3.0e38f, m2 = 3.0e38f, m3 = 3.0e38f;

    // phase A: slabs b0-1 .. b0+1 -> upper bound
    const int sA = base[(b0 > 0) ? b0 - 1 : 0];
    const int eA = base[(b0 + 2 < NB) ? b0 + 2 : NB];
    for (int j = sA + lane; j < eA; j += 64) {
        const float4 p = pts[j];
        m0 = fminf(m0, fabsf(qx - p.x) + fabsf(qy - p.y) + fabsf(qz - p.z));
    }
    float m = fminf(fminf(m0, m1), fminf(m2, m3));
#pragma unroll
    for (int k = 1; k < 64; k <<= 1) m = fminf(m, __shfl_xor(m, k, 64));

    // phase B window (monotone bucket map + slack) minus the phase-A range
    const int bl0 = (int)fminf(fmaxf((qx - m - lo) * invw, 0.0f), (float)(NB - 1));
    const int br0 = (int)fminf(fmaxf((qx + m - lo) * invw, 0.0f), (float)(NB - 1));
    const int bl = (bl0 > 0) ? bl0 - 1 : 0;
    const int br = (br0 + 1 < NB - 1) ? br0 + 1 : NB - 1;
    const int sW = base[bl], eW = base[br + 1];

    m0 = m;
    // two segments: [sW, sA) and [eA, eW); 4-way unrolled, uniform trip count
#pragma unroll 1
    for (int seg = 0; seg < 2; ++seg) {
        const int s = seg ? eA : sW;
        const int e = seg ? eW : sA;
        const int n = e - s;
        if (n <= 0) continue;
        const float4* __restrict__ p = pts + s;
        const int nb4 = n >> 8;            // batches of 256 (64 lanes x 4)
        int j = lane;
        for (int b = 0; b < nb4; ++b, j += 256) {
            const float4 a0 = p[j];
            const float4 a1 = p[j + 64];
            const float4 a2 = p[j + 128];
            const float4 a3 = p[j + 192];
            m0 = fminf(m0, fabsf(qx - a0.x) + fabsf(qy - a0.y) + fabsf(qz - a0.z));
            m1 = fminf(m1, fabsf(qx - a1.x) + fabsf(qy - a1.y) + fabsf(qz - a1.z));
            m2 = fminf(m2, fabsf(qx - a2.x) + fabsf(qy - a2.y) + fabsf(qz - a2.z));
            m3 = fminf(m3, fabsf(qx - a3.x) + fabsf(qy - a3.y) + fabsf(qz - a3.z));
        }
        for (; j < n; j += 64) {
            const float4 a = p[j];
            m0 = fminf(m0, fabsf(qx - a.x) + fabsf(qy - a.y) + fabsf(qz - a.z));
        }
    }
    m = fminf(fminf(m0, m1), fminf(m2, m3));
#pragma unroll
    for (int k = 1; k < 64; k <<= 1) m = fminf(m, __shfl_xor(m, k, 64));

    if (lane == 0) {
        qmin[q] = m;
        out[1 + q] = 0.0f;      // freespace_loss zeros, written here for free
    }
}

// single block: out[0] = sum(qmin)/N
__global__ __launch_bounds__(FTPB) void finalize_kernel(
    const float* __restrict__ qmin, float* __restrict__ out, int N, float invN) {
    const int t = threadIdx.x;
    float s = 0.0f;
    const float4* p4 = (const float4*)qmin;
    const int n4 = N >> 2;
    for (int k = t; k < n4; k += FTPB) {
        const float4 v = p4[k];
        s += v.x + v.y + v.z + v.w;
    }
    for (int k = (n4 << 2) + t; k < N; k += FTPB) s += qmin[k];
#pragma unroll
    for (int off = 32; off; off >>= 1) s += __shfl_down(s, off, 64);
    __shared__ float ls[FTPB / 64];
    if ((t & 63) == 0) ls[t >> 6] = s;
    __syncthreads();
    if (t == 0) {
        float tot = 0.0f;
        for (int w2 = 0; w2 < FTPB / 64; ++w2) tot += ls[w2];
        out[0] = tot * invN;
    }
}

extern "C" void kernel_launch(void* const* d_in, const int* in_sizes, int n_in,
                              void* d_out, int out_size, void* d_ws, size_t ws_size,
                              hipStream_t stream) {
    const float* pc1  = (const float*)d_in[0];
    const float* flow = (const float*)d_in[1];
    const float* pc2  = (const float*)d_in[2];
    float* out = (float*)d_out;

    const int N = in_sizes[0] / 3;
    const int M = in_sizes[2] / 3;

    char* ws = (char*)d_ws;
    float*  hdr  = (float*)ws;                         // 2 floats
    int*    base = (int*)(ws + 64);                    // NB+1 ints
    float4* pts  = (float4*)(ws + 4096);               // M float4
    float*  qmin = (float*)(ws + 4096 + (size_t)M * 16);

    build_kernel<<<1, BTPB, 0, stream>>>(pc2, pts, base, hdr, M);

    const int qblocks = (N + (QTPB / 64) - 1) / (QTPB / 64);   // 4096
    query_kernel<<<qblocks, QTPB, 0, stream>>>(pc1, flow, pts, base, hdr, qmin, out, N);

    finalize_kernel<<<1, FTPB, 0, stream>>>(qmin, out, N, 1.0f / (float)N);
}